// Round 5
// baseline (252.428 us; speedup 1.0000x reference)
//
#include <hip/hip_runtime.h>
#include <hip/hip_bf16.h>
#include <math.h>

#define NROWS 131072
#define NCOLS 360               // 90 float4 per row
#define ROWS_PER_WAVE 8
#define NWAVES (NROWS / ROWS_PER_WAVE)      // 16384
#define NBLOCKS (NWAVES / 4)                // 4096

typedef float f32x4 __attribute__((ext_vector_type(4)));

// One wave per row, 8 rows per wave, processed 4 at a time so the four
// rows' shuffle-reduction chains (the latency-bound part) fully interleave
// and 8 nontemporal loads are in flight per wave. Row = 90 float4: lane i
// holds f4[i], lanes 0..25 also f4[64+i]. Single streaming read of preds;
// no max-subtraction (|x|/sum|x| in [-1,1]); native exp/log; label value
// pulled from registers via shuffle.
__global__ __launch_bounds__(256) void viewpoint_row_kernel(
    const float* __restrict__ preds,
    const int* __restrict__ labels,
    float* __restrict__ partial)
{
    const int wave = threadIdx.x >> 6;
    const int lane = threadIdx.x & 63;
    const int wgid = blockIdx.x * 4 + wave;            // 0..NWAVES-1
    const bool have2 = lane < (90 - 64);               // lanes 0..25

    float gacc = 0.f;

    #pragma unroll
    for (int r = 0; r < ROWS_PER_WAVE; r += 4) {
        int rows[4];
        const f32x4* p[4];
        f32x4 lo[4], hi[4];
        #pragma unroll
        for (int j = 0; j < 4; ++j) {
            rows[j] = (r + j) * NWAVES + wgid;
            p[j] = (const f32x4*)(preds + (size_t)rows[j] * NCOLS);
        }
        #pragma unroll
        for (int j = 0; j < 4; ++j)
            lo[j] = __builtin_nontemporal_load(p[j] + lane);
        #pragma unroll
        for (int j = 0; j < 4; ++j) {
            hi[j] = (f32x4){0.f, 0.f, 0.f, 0.f};
            if (have2) hi[j] = __builtin_nontemporal_load(p[j] + 64 + lane);
        }

        // ---- per-lane sum |x|, four independent chains ----
        float s[4];
        #pragma unroll
        for (int j = 0; j < 4; ++j)
            s[j] = (fabsf(lo[j].x) + fabsf(lo[j].y)) + (fabsf(lo[j].z) + fabsf(lo[j].w))
                 + ((fabsf(hi[j].x) + fabsf(hi[j].y)) + (fabsf(hi[j].z) + fabsf(hi[j].w)));

        #pragma unroll
        for (int off = 32; off > 0; off >>= 1) {
            #pragma unroll
            for (int j = 0; j < 4; ++j) s[j] += __shfl_xor(s[j], off);
        }

        float inv[4];
        #pragma unroll
        for (int j = 0; j < 4; ++j) inv[j] = __builtin_amdgcn_rcpf(s[j]);

        // ---- sum exp(x * inv); args bounded in [-1,1], no max needed ----
        float e[4];
        #pragma unroll
        for (int j = 0; j < 4; ++j) {
            e[j] = (__expf(lo[j].x * inv[j]) + __expf(lo[j].y * inv[j]))
                 + (__expf(lo[j].z * inv[j]) + __expf(lo[j].w * inv[j]));
            if (have2)
                e[j] += (__expf(hi[j].x * inv[j]) + __expf(hi[j].y * inv[j]))
                      + (__expf(hi[j].z * inv[j]) + __expf(hi[j].w * inv[j]));
        }
        #pragma unroll
        for (int off = 32; off > 0; off >>= 1) {
            #pragma unroll
            for (int j = 0; j < 4; ++j) e[j] += __shfl_xor(e[j], off);
        }

        // ---- x[label] from registers (labels[row] is wave-uniform) ----
        #pragma unroll
        for (int j = 0; j < 4; ++j) {
            const int lab = labels[rows[j]];
            const int f4i = lab >> 2, c = lab & 3;
            const f32x4 src = (f4i < 64) ? lo[j] : hi[j];
            const int owner = (f4i < 64) ? f4i : (f4i - 64);
            const float v = (c == 0) ? src.x : (c == 1) ? src.y
                          : (c == 2) ? src.z : src.w;
            gacc += __shfl(v, owner) * inv[j] - __logf(e[j]);
        }
    }

    __shared__ float sh[4];
    if (lane == 0) sh[wave] = gacc;
    __syncthreads();
    if (threadIdx.x == 0)
        partial[blockIdx.x] = sh[0] + sh[1] + sh[2] + sh[3];
}

// Single-block final reduction of 4096 per-block partials (float4 loads).
__global__ __launch_bounds__(256) void viewpoint_final_kernel(
    const float* __restrict__ partial, float* __restrict__ out, int n4)
{
    const f32x4* p4 = (const f32x4*)partial;
    float s = 0.f;
    for (int i = threadIdx.x; i < n4; i += 256) {
        f32x4 v = p4[i];
        s += (v.x + v.y) + (v.z + v.w);
    }
    #pragma unroll
    for (int off = 32; off > 0; off >>= 1) s += __shfl_xor(s, off);
    __shared__ float sh[4];
    if ((threadIdx.x & 63) == 0) sh[threadIdx.x >> 6] = s;
    __syncthreads();
    if (threadIdx.x == 0)
        out[0] = -(sh[0] + sh[1] + sh[2] + sh[3]) * (1.0f / (float)NCOLS);
}

extern "C" void kernel_launch(void* const* d_in, const int* in_sizes, int n_in,
                              void* d_out, int out_size, void* d_ws, size_t ws_size,
                              hipStream_t stream) {
    const float* preds  = (const float*)d_in[0];
    const int*   labels = (const int*)d_in[1];
    float* out = (float*)d_out;
    float* partial = (float*)d_ws;                      // 4096 floats = 16 KB

    viewpoint_row_kernel<<<NBLOCKS, 256, 0, stream>>>(preds, labels, partial);
    viewpoint_final_kernel<<<1, 256, 0, stream>>>(partial, out, NBLOCKS / 4);
}

// Round 6
// 248.398 us; speedup vs baseline: 1.0162x; 1.0162x over previous
//
#include <hip/hip_runtime.h>
#include <hip/hip_bf16.h>
#include <math.h>

#define NROWS 131072
#define NCOLS 360               // 90 float4 per row
#define ROWS_PER_WAVE 8
#define NWAVES (NROWS / ROWS_PER_WAVE)      // 16384
#define NBLOCKS (NWAVES / 4)                // 4096

typedef float f32x4 __attribute__((ext_vector_type(4)));

// One wave per row, 8 rows per wave, processed in PAIRS so the two rows'
// shuffle-reduction chains (the latency-bound part) interleave. Row = 90
// float4: lane i holds f4[i], lanes 0..25 also f4[64+i]. Single streaming
// read of preds; no max-subtraction (|x|/sum|x| in [-1,1]); native exp/log;
// label value pulled from registers via shuffle.
// NOTE: 4-wide interleave was tried (R5) and regressed +3.8us — VGPR
// pressure outweighs extra ILP; 2-wide is the measured sweet spot.
__global__ __launch_bounds__(256) void viewpoint_row_kernel(
    const float* __restrict__ preds,
    const int* __restrict__ labels,
    float* __restrict__ partial)
{
    const int wave = threadIdx.x >> 6;
    const int lane = threadIdx.x & 63;
    const int wgid = blockIdx.x * 4 + wave;            // 0..NWAVES-1
    const bool have2 = lane < (90 - 64);               // lanes 0..25

    float gacc = 0.f;

    #pragma unroll
    for (int r = 0; r < ROWS_PER_WAVE; r += 2) {
        const int rowA = r * NWAVES + wgid;
        const int rowB = (r + 1) * NWAVES + wgid;
        const f32x4* pA = (const f32x4*)(preds + (size_t)rowA * NCOLS);
        const f32x4* pB = (const f32x4*)(preds + (size_t)rowB * NCOLS);

        f32x4 a0 = __builtin_nontemporal_load(pA + lane);
        f32x4 b0 = __builtin_nontemporal_load(pB + lane);
        f32x4 a1 = {0.f, 0.f, 0.f, 0.f};
        f32x4 b1 = {0.f, 0.f, 0.f, 0.f};
        if (have2) {
            a1 = __builtin_nontemporal_load(pA + 64 + lane);
            b1 = __builtin_nontemporal_load(pB + 64 + lane);
        }

        // ---- per-lane sum |x| for both rows (abs folds into VOP3 mods) ----
        float sA = (fabsf(a0.x) + fabsf(a0.y)) + (fabsf(a0.z) + fabsf(a0.w))
                 + ((fabsf(a1.x) + fabsf(a1.y)) + (fabsf(a1.z) + fabsf(a1.w)));
        float sB = (fabsf(b0.x) + fabsf(b0.y)) + (fabsf(b0.z) + fabsf(b0.w))
                 + ((fabsf(b1.x) + fabsf(b1.y)) + (fabsf(b1.z) + fabsf(b1.w)));

        // interleaved butterflies — two independent chains
        #pragma unroll
        for (int off = 32; off > 0; off >>= 1) {
            sA += __shfl_xor(sA, off);
            sB += __shfl_xor(sB, off);
        }

        const float invA = __builtin_amdgcn_rcpf(sA);
        const float invB = __builtin_amdgcn_rcpf(sB);

        // ---- sum exp(x * inv); args bounded in [-1,1], no max needed ----
        float eA = (__expf(a0.x * invA) + __expf(a0.y * invA))
                 + (__expf(a0.z * invA) + __expf(a0.w * invA));
        float eB = (__expf(b0.x * invB) + __expf(b0.y * invB))
                 + (__expf(b0.z * invB) + __expf(b0.w * invB));
        if (have2) {
            eA += (__expf(a1.x * invA) + __expf(a1.y * invA))
                + (__expf(a1.z * invA) + __expf(a1.w * invA));
            eB += (__expf(b1.x * invB) + __expf(b1.y * invB))
                + (__expf(b1.z * invB) + __expf(b1.w * invB));
        }
        #pragma unroll
        for (int off = 32; off > 0; off >>= 1) {
            eA += __shfl_xor(eA, off);
            eB += __shfl_xor(eB, off);
        }

        // ---- x[label] from registers (labels[row] is wave-uniform) ----
        {
            const int lab = labels[rowA];
            const int f4i = lab >> 2, c = lab & 3;
            const f32x4 src = (f4i < 64) ? a0 : a1;
            const int owner = (f4i < 64) ? f4i : (f4i - 64);
            const float v = (c == 0) ? src.x : (c == 1) ? src.y
                          : (c == 2) ? src.z : src.w;
            gacc += __shfl(v, owner) * invA - __logf(eA);
        }
        {
            const int lab = labels[rowB];
            const int f4i = lab >> 2, c = lab & 3;
            const f32x4 src = (f4i < 64) ? b0 : b1;
            const int owner = (f4i < 64) ? f4i : (f4i - 64);
            const float v = (c == 0) ? src.x : (c == 1) ? src.y
                          : (c == 2) ? src.z : src.w;
            gacc += __shfl(v, owner) * invB - __logf(eB);
        }
    }

    __shared__ float sh[4];
    if (lane == 0) sh[wave] = gacc;
    __syncthreads();
    if (threadIdx.x == 0)
        partial[blockIdx.x] = sh[0] + sh[1] + sh[2] + sh[3];
}

// Single-block final reduction of 4096 per-block partials (float4 loads).
__global__ __launch_bounds__(256) void viewpoint_final_kernel(
    const float* __restrict__ partial, float* __restrict__ out, int n4)
{
    const f32x4* p4 = (const f32x4*)partial;
    float s = 0.f;
    for (int i = threadIdx.x; i < n4; i += 256) {
        f32x4 v = p4[i];
        s += (v.x + v.y) + (v.z + v.w);
    }
    #pragma unroll
    for (int off = 32; off > 0; off >>= 1) s += __shfl_xor(s, off);
    __shared__ float sh[4];
    if ((threadIdx.x & 63) == 0) sh[threadIdx.x >> 6] = s;
    __syncthreads();
    if (threadIdx.x == 0)
        out[0] = -(sh[0] + sh[1] + sh[2] + sh[3]) * (1.0f / (float)NCOLS);
}

extern "C" void kernel_launch(void* const* d_in, const int* in_sizes, int n_in,
                              void* d_out, int out_size, void* d_ws, size_t ws_size,
                              hipStream_t stream) {
    const float* preds  = (const float*)d_in[0];
    const int*   labels = (const int*)d_in[1];
    float* out = (float*)d_out;
    float* partial = (float*)d_ws;                      // 4096 floats = 16 KB

    viewpoint_row_kernel<<<NBLOCKS, 256, 0, stream>>>(preds, labels, partial);
    viewpoint_final_kernel<<<1, 256, 0, stream>>>(partial, out, NBLOCKS / 4);
}